// Round 4
// baseline (60.105 us; speedup 1.0000x reference)
//
#include <hip/hip_runtime.h>

typedef float f4 __attribute__((ext_vector_type(4)));
typedef float f2 __attribute__((ext_vector_type(2)));
typedef short short8 __attribute__((ext_vector_type(8)));
typedef float f32x4 __attribute__((ext_vector_type(4)));

#define NEG_INF -1e9f

// ---------------------------------------------------------------------------
// bf16 split: x ~= hi + lo, both bf16 (RNE). 3-pass MFMA gives ~2^-16 accuracy.
// ---------------------------------------------------------------------------
__device__ inline void bsplit(float x, unsigned short& h, unsigned short& l) {
  union { float f; unsigned u; } a; a.f = x;
  unsigned rh = (a.u + 0x7fffu + ((a.u >> 16) & 1u)) >> 16;
  h = (unsigned short)rh;
  union { unsigned u; float f; } b; b.u = rh << 16;
  union { float f; unsigned u; } c; c.f = x - b.f;
  unsigned rl = (c.u + 0x7fffu + ((c.u >> 16) & 1u)) >> 16;
  l = (unsigned short)rl;
}

__device__ inline void gl_lds16(const void* g, void* l) {
  __builtin_amdgcn_global_load_lds(
      (const __attribute__((address_space(1))) unsigned int*)g,
      (__attribute__((address_space(3))) unsigned int*)l, 16, 0, 0);
}

// ---------------------------------------------------------------------------
// conv_a: pack X = {query rows 0..1023, value rows 0..1023} into
// A_perm[panel 32][kchunk 64][row 64][8] bf16 (hi & lo). panel = rows/64.
// ---------------------------------------------------------------------------
__global__ __launch_bounds__(256) void conv_a(
    const float* __restrict__ q, const float* __restrict__ v,
    unsigned short* __restrict__ Ahi, unsigned short* __restrict__ Alo)
{
  const int g = blockIdx.x * 256 + threadIdx.x;   // 131072 total
  const int row64 = g & 63;
  const int panel = (g >> 6) & 31;
  const int kc    = g >> 11;                       // 0..63
  const int rowg  = panel * 64 + row64;
  const float* src = (rowg < 1024) ? (q + (size_t)rowg * 512 + kc * 8)
                                   : (v + (size_t)(rowg - 1024) * 512 + kc * 8);
  f4 x0 = *reinterpret_cast<const f4*>(src);
  f4 x1 = *reinterpret_cast<const f4*>(src + 4);
  unsigned short h[8], l[8];
#pragma unroll
  for (int j = 0; j < 4; ++j) { bsplit(x0[j], h[j], l[j]); bsplit(x1[j], h[4+j], l[4+j]); }
  const size_t off = ((size_t)(panel * 64 + kc) * 64 + row64) * 8;
  short8 ph, pl;
#pragma unroll
  for (int j = 0; j < 8; ++j) { ph[j] = (short)h[j]; pl[j] = (short)l[j]; }
  *reinterpret_cast<short8*>(&Ahi[off]) = ph;
  *reinterpret_cast<short8*>(&Alo[off]) = pl;
}

// ---------------------------------------------------------------------------
// conv_w: W[z][512 k][512 n] -> Wt_perm[wpanel=z*8+np][kchunk 64][n 64][8] bf16
// (transpose via LDS tile).
// ---------------------------------------------------------------------------
__global__ __launch_bounds__(256) void conv_w(
    const float* __restrict__ W1, const float* __restrict__ W2,
    unsigned short* __restrict__ Whi, unsigned short* __restrict__ Wlo)
{
  const int kslab = blockIdx.x;      // 0..3   (128 k each)
  const int np    = blockIdx.y;      // 0..7   (64 n each)
  const int z     = blockIdx.z;      // 0..1
  const float* __restrict__ W = z ? W2 : W1;
  const int k0 = kslab * 128, n0 = np * 64;
  const int t = threadIdx.x;

  __shared__ float ldsW[128][64];
#pragma unroll
  for (int it = 0; it < 8; ++it) {
    const int idx = it * 256 + t;
    const int kr  = idx >> 4;
    const int nc4 = (idx & 15) * 4;
    *reinterpret_cast<f4*>(&ldsW[kr][nc4]) =
        *reinterpret_cast<const f4*>(&W[(size_t)(k0 + kr) * 512 + n0 + nc4]);
  }
  __syncthreads();

  const int wpanel = z * 8 + np;
  const int n = t & 63;
#pragma unroll
  for (int it = 0; it < 4; ++it) {
    const int kcl = it * 4 + (t >> 6);            // 0..15
    short8 ph, pl;
#pragma unroll
    for (int j = 0; j < 8; ++j) {
      unsigned short h, l;
      bsplit(ldsW[kcl * 8 + j][n], h, l);
      ph[j] = (short)h; pl[j] = (short)l;
    }
    const size_t off = ((size_t)(wpanel * 64 + kslab * 16 + kcl) * 64 + n) * 8;
    *reinterpret_cast<short8*>(&Whi[off]) = ph;
    *reinterpret_cast<short8*>(&Wlo[off]) = pl;
  }
}

// ---------------------------------------------------------------------------
// projmm: C = X @ W via 3-pass bf16-split MFMA (16x16x32), exp(2x) epilogue.
// (unchanged this round — clean A/B on bah_attn)
// ---------------------------------------------------------------------------
__global__ __launch_bounds__(256) void projmm(
    const unsigned short* __restrict__ Ahi, const unsigned short* __restrict__ Alo,
    const unsigned short* __restrict__ Whi, const unsigned short* __restrict__ Wlo,
    float* __restrict__ EQ, float* __restrict__ EKT)
{
  const int nb = blockIdx.x, mb = blockIdx.y, z = blockIdx.z;
  const int t = threadIdx.x;
  const int l = t & 63;
  const int w = t >> 6;
  const int wr = w >> 1, wc = w & 1;

  __shared__ __align__(16) short Ast[2][2][2048];  // [buf][hi/lo][4kg*64row*8]
  __shared__ __align__(16) short Bst[2][2][2048];
  __shared__ float ldsT[64][67];

  const unsigned short* abase_h = Ahi + (size_t)(z * 16 + mb) * 32768;
  const unsigned short* abase_l = Alo + (size_t)(z * 16 + mb) * 32768;
  const unsigned short* wbase_h = Whi + (size_t)(z * 8 + nb) * 32768;
  const unsigned short* wbase_l = Wlo + (size_t)(z * 8 + nb) * 32768;

  const int ldst = (t >> 6) * 512;   // wave-uniform LDS dest base (shorts)
  const int gsrc = t * 8;            // per-lane global offset (shorts)

#define STAGE(buf, ks)                                                        \
  do {                                                                        \
    gl_lds16(abase_h + (ks) * 2048 + gsrc, &Ast[buf][0][ldst]);               \
    gl_lds16(abase_l + (ks) * 2048 + gsrc, &Ast[buf][1][ldst]);               \
    gl_lds16(wbase_h + (ks) * 2048 + gsrc, &Bst[buf][0][ldst]);               \
    gl_lds16(wbase_l + (ks) * 2048 + gsrc, &Bst[buf][1][ldst]);               \
  } while (0)

  f32x4 acc[2][2] = {};
  STAGE(0, 0);
  __syncthreads();

  int buf = 0;
  for (int ks = 0; ks < 16; ++ks) {
    if (ks < 15) STAGE(buf ^ 1, ks + 1);
    const int kgo = (l >> 4) * 1024;
    short8 ah[2], al[2], bh[2], bl[2];
#pragma unroll
    for (int i = 0; i < 2; ++i) {
      const int ro = (wr * 32 + i * 16 + (l & 15)) * 16;
      ah[i] = *reinterpret_cast<const short8*>((const char*)&Ast[buf][0][0] + kgo + ro);
      al[i] = *reinterpret_cast<const short8*>((const char*)&Ast[buf][1][0] + kgo + ro);
    }
#pragma unroll
    for (int j = 0; j < 2; ++j) {
      const int co = (wc * 32 + j * 16 + (l & 15)) * 16;
      bh[j] = *reinterpret_cast<const short8*>((const char*)&Bst[buf][0][0] + kgo + co);
      bl[j] = *reinterpret_cast<const short8*>((const char*)&Bst[buf][1][0] + kgo + co);
    }
#pragma unroll
    for (int i = 0; i < 2; ++i)
#pragma unroll
      for (int j = 0; j < 2; ++j) {
        acc[i][j] = __builtin_amdgcn_mfma_f32_16x16x32_bf16(ah[i], bh[j], acc[i][j], 0, 0, 0);
        acc[i][j] = __builtin_amdgcn_mfma_f32_16x16x32_bf16(ah[i], bl[j], acc[i][j], 0, 0, 0);
        acc[i][j] = __builtin_amdgcn_mfma_f32_16x16x32_bf16(al[i], bh[j], acc[i][j], 0, 0, 0);
      }
    __syncthreads();
    buf ^= 1;
  }

  if (z == 0) {
#pragma unroll
    for (int i = 0; i < 2; ++i)
#pragma unroll
      for (int j = 0; j < 2; ++j)
#pragma unroll
        for (int r = 0; r < 4; ++r) {
          const int row = mb * 64 + wr * 32 + i * 16 + (l >> 4) * 4 + r;
          const int col = nb * 64 + wc * 32 + j * 16 + (l & 15);
          EQ[(size_t)row * 512 + col] = __expf(2.0f * acc[i][j][r]);
        }
  } else {
#pragma unroll
    for (int i = 0; i < 2; ++i)
#pragma unroll
      for (int j = 0; j < 2; ++j)
#pragma unroll
        for (int r = 0; r < 4; ++r) {
          const int rl = wr * 32 + i * 16 + (l >> 4) * 4 + r;   // v-local
          const int cl = wc * 32 + j * 16 + (l & 15);           // u-local
          ldsT[rl][cl] = __expf(2.0f * acc[i][j][r]);
        }
    __syncthreads();
    const int b  = (mb * 64) >> 8;
    const int v0 = (mb * 64) & 255;
    const int vl = t & 63;
#pragma unroll
    for (int it = 0; it < 16; ++it) {
      const int ul = it * 4 + (t >> 6);
      EKT[(size_t)b * 131072 + (size_t)(nb * 64 + ul) * 256 + v0 + vl] = ldsT[vl][ul];
    }
  }
#undef STAGE
}

// ---------------------------------------------------------------------------
// bah_attn v4: 512 blocks (b, tq-PAIR), 512 threads = 8 waves, 2 blocks/CU.
// Thread: v4 = tid&63 (4 v's), u-slab = wave (64 u's), 2 q-rows.
// Paired-rcp: s0/d0 + s1/d1 = (s0*d1 + s1*d0) * rcp(d0*d1)  -> 1 rcp / 2 evals.
// score = sumS - 2 * sum_u s_u * rcp(eq*ek + 1).
// ---------------------------------------------------------------------------
__global__ __launch_bounds__(512, 4) void bah_attn(
    const float* __restrict__ EQ, const float* __restrict__ EKT,
    const float* __restrict__ value, const int* __restrict__ mask,
    const float* __restrict__ scale,
    float* __restrict__ ctx_out, float* __restrict__ attn_out)
{
  const int blk = blockIdx.x;
  // XCD-aware: default map XCD = blk%8; blocks of one batch b stay on 2 XCDs.
  const int b   = (blk & 7) >> 1;
  const int tqp = (blk >> 3) + ((blk & 1) << 6);   // 0..127
  const int bq  = b * 256 + tqp * 2;

  const int tid = threadIdx.x;
  const int l   = tid & 63;
  const int w   = tid >> 6;        // wave 0..7 = u-slab
  const int v4  = l;               // 4 v's per thread

  __shared__ f2    eq2s[512];            // {row0,row1} per u     4 KB
  __shared__ float ss[512];              //                       2 KB
  __shared__ float part[8][2][256];      // [uslab][row][v]      16 KB
  __shared__ float wredM[2][4];
  __shared__ float wredS[2][4];
  __shared__ float sumS_lds;
  __shared__ float atT[256][2];          //                       2 KB
  __shared__ float ctxp[4][2][512];      // [vchunk][row][d]     16 KB

  const float* __restrict__ ekb = EKT + (size_t)b * (512 * 256);
  const float* __restrict__ eqb = EQ + (size_t)bq * 512;

  {
    f2 e; e[0] = eqb[tid]; e[1] = eqb[512 + tid];
    eq2s[tid] = e;
    ss[tid] = scale[tid];
  }
  __syncthreads();

  if (w == 0) {
    float s = 0.f;
#pragma unroll
    for (int j = 0; j < 8; ++j) s += ss[l + 64 * j];
#pragma unroll
    for (int off = 32; off; off >>= 1) s += __shfl_xor(s, off);
    if (l == 0) sumS_lds = s;
  }

  // ---- main loop: 64 u's (32 pairs) x 4 v's x 2 rows per thread ----
  f4 acc0 = {0.f, 0.f, 0.f, 0.f};
  f4 acc1 = {0.f, 0.f, 0.f, 0.f};
  const int u0 = w * 64;
  const float* __restrict__ pek = ekb + (size_t)u0 * 256 + v4 * 4;
#pragma unroll 2
  for (int up = 0; up < 32; ++up) {
    const f4 ekA = *reinterpret_cast<const f4*>(pek + (size_t)(2 * up) * 256);
    const f4 ekB = *reinterpret_cast<const f4*>(pek + (size_t)(2 * up + 1) * 256);
    const f2 eqA = eq2s[u0 + 2 * up];
    const f2 eqB = eq2s[u0 + 2 * up + 1];
    const f2 sp  = *reinterpret_cast<const f2*>(&ss[u0 + 2 * up]);
#pragma unroll
    for (int j = 0; j < 4; ++j) {
      const float d0 = fmaf(eqA[0], ekA[j], 1.0f);
      const float d1 = fmaf(eqB[0], ekB[j], 1.0f);
      const float n0 = fmaf(sp[0], d1, sp[1] * d0);
      acc0[j] = fmaf(n0, __builtin_amdgcn_rcpf(d0 * d1), acc0[j]);
      const float e0 = fmaf(eqA[1], ekA[j], 1.0f);
      const float e1 = fmaf(eqB[1], ekB[j], 1.0f);
      const float n1 = fmaf(sp[0], e1, sp[1] * e0);
      acc1[j] = fmaf(n1, __builtin_amdgcn_rcpf(e0 * e1), acc1[j]);
    }
  }
  *reinterpret_cast<f4*>(&part[w][0][v4 * 4]) = acc0;
  *reinterpret_cast<f4*>(&part[w][1][v4 * 4]) = acc1;
  __syncthreads();

  // ---- masked softmax: all 512 threads (row = tid>>8, v = tid&255) ----
  const int r  = tid >> 8;
  const int v  = tid & 255;
  const int w4 = (tid >> 6) & 3;
  float sc, ex;
  {
    float p = 0.f;
#pragma unroll
    for (int u2 = 0; u2 < 8; ++u2) p += part[u2][r][v];
    const bool mok = (mask[b * 256 + v] != 0);
    sc = mok ? (sumS_lds - 2.0f * p) : NEG_INF;
    float m = sc;
#pragma unroll
    for (int off = 32; off; off >>= 1) m = fmaxf(m, __shfl_xor(m, off));
    if (l == 0) wredM[r][w4] = m;
  }
  __syncthreads();
  {
    const float m = fmaxf(fmaxf(wredM[r][0], wredM[r][1]),
                          fmaxf(wredM[r][2], wredM[r][3]));
    ex = __expf(sc - m);
    float sm = ex;
#pragma unroll
    for (int off = 32; off; off >>= 1) sm += __shfl_xor(sm, off);
    if (l == 0) wredS[r][w4] = sm;
  }
  __syncthreads();
  {
    const float denom = (wredS[r][0] + wredS[r][1]) + (wredS[r][2] + wredS[r][3]);
    const float a = ex * __builtin_amdgcn_rcpf(denom);
    atT[v][r] = a;
    attn_out[(size_t)(bq + r) * 256 + v] = a;
  }
  __syncthreads();

  // ---- context: 8 waves = 2 rows x 4 v-chunks; lanes span all 512 d ----
  const int cr = w >> 2;           // row
  const int vc = w & 3;            // v-chunk of 64
  const float* __restrict__ vb = value + (size_t)b * (256 * 512);
  f4 c0 = {0.f, 0.f, 0.f, 0.f};
  f4 c1 = {0.f, 0.f, 0.f, 0.f};
  for (int v2 = 0; v2 < 64; ++v2) {
    const int vv = vc * 64 + v2;
    const float a = atT[vv][cr];                 // LDS broadcast
    const f4 x0 = *reinterpret_cast<const f4*>(&vb[(size_t)vv * 512 + l * 4]);
    const f4 x1 = *reinterpret_cast<const f4*>(&vb[(size_t)vv * 512 + 256 + l * 4]);
    c0 += a * x0;
    c1 += a * x1;
  }
  *reinterpret_cast<f4*>(&ctxp[vc][cr][l * 4]) = c0;
  *reinterpret_cast<f4*>(&ctxp[vc][cr][256 + l * 4]) = c1;
  __syncthreads();

  // ---- final reduce over v-chunks + f2 store ----
  {
    const int row = tid >> 8;
    const int d2  = (tid & 255) * 2;
    const f2 s0 = *reinterpret_cast<const f2*>(&ctxp[0][row][d2]);
    const f2 s1 = *reinterpret_cast<const f2*>(&ctxp[1][row][d2]);
    const f2 s2 = *reinterpret_cast<const f2*>(&ctxp[2][row][d2]);
    const f2 s3 = *reinterpret_cast<const f2*>(&ctxp[3][row][d2]);
    const f2 rr = (s0 + s1) + (s2 + s3);
    *reinterpret_cast<f2*>(&ctx_out[(size_t)(bq + row) * 512 + d2]) = rr;
  }
}

// ---------------------------------------------------------------------------
extern "C" void kernel_launch(void* const* d_in, const int* in_sizes, int n_in,
                              void* d_out, int out_size, void* d_ws, size_t ws_size,
                              hipStream_t stream) {
  const float* query = (const float*)d_in[0];
  const float* value = (const float*)d_in[1];
  const int*   mask  = (const int*)d_in[2];
  const float* W1    = (const float*)d_in[3];
  const float* W2    = (const float*)d_in[4];
  const float* scale = (const float*)d_in[5];

  char* ws = (char*)d_ws;
  float* EQ  = (float*)(ws);                         // 2 MB  [1024][512]
  float* EKT = (float*)(ws + (2u << 20));            // 2 MB  [4][512][256]
  unsigned short* Ahi = (unsigned short*)(ws + (4u << 20));   // 2 MB
  unsigned short* Alo = (unsigned short*)(ws + (6u << 20));   // 2 MB
  unsigned short* Whi = (unsigned short*)(ws + (8u << 20));   // 1 MB
  unsigned short* Wlo = (unsigned short*)(ws + (9u << 20));   // 1 MB

  float* ctx  = (float*)d_out;          // [4][256][512]
  float* attn = ctx + 4 * 256 * 512;    // [4][256][256]

  conv_a<<<dim3(512), 256, 0, stream>>>(query, value, Ahi, Alo);
  conv_w<<<dim3(4, 8, 2), 256, 0, stream>>>(W1, W2, Whi, Wlo);
  projmm<<<dim3(8, 16, 2), 256, 0, stream>>>(Ahi, Alo, Whi, Wlo, EQ, EKT);
  bah_attn<<<dim3(512), 512, 0, stream>>>(EQ, EKT, value, mask, scale, ctx, attn);
}